// Round 1
// baseline (523.140 us; speedup 1.0000x reference)
//
#include <hip/hip_runtime.h>

#define N_Q    20
#define DIM    (1 << N_Q)      // 1048576
#define BATCH  4
#define NGATES 19
#define L2OFF  117             // 6n-3 : second xyz layer offset

typedef float2 c32;

__device__ __forceinline__ c32 cmul(c32 a, c32 b) {
    return make_float2(fmaf(a.x, b.x, -a.y * b.y), fmaf(a.x, b.y, a.y * b.x));
}
__device__ __forceinline__ c32 cmadd(c32 acc, c32 a, c32 b) {
    acc.x = fmaf(a.x, b.x, fmaf(-a.y, b.y, acc.x));
    acc.y = fmaf(a.x, b.y, fmaf(a.y, b.x, acc.y));
    return acc;
}

__device__ void mm2(const c32 A[2][2], const c32 B[2][2], c32 C[2][2]) {
    for (int i = 0; i < 2; i++)
        for (int j = 0; j < 2; j++) {
            c32 s = make_float2(0.f, 0.f);
            for (int k = 0; k < 2; k++) s = cmadd(s, A[i][k], B[k][j]);
            C[i][j] = s;
        }
}
__device__ void mm4(const c32 A[4][4], const c32 B[4][4], c32 C[4][4]) {
    for (int i = 0; i < 4; i++)
        for (int j = 0; j < 4; j++) {
            c32 s = make_float2(0.f, 0.f);
            for (int k = 0; k < 4; k++) s = cmadd(s, A[i][k], B[k][j]);
            C[i][j] = s;
        }
}
// fused RZ*RY*RX for one qubit; w[base..base+2] = (theta_x, theta_y, theta_z)
__device__ void single_u(const float* w, int base, c32 U[2][2]) {
    const float WM = 0.63245553203367586640f;  // sqrt(2/5)
    float hx = w[base] * WM * 0.5f, hy = w[base + 1] * WM * 0.5f, hz = w[base + 2] * WM * 0.5f;
    float cx = cosf(hx), sx = sinf(hx);
    float cy = cosf(hy), sy = sinf(hy);
    float cz = cosf(hz), sz = sinf(hz);
    c32 RX[2][2] = {{{cx, 0.f}, {0.f, -sx}}, {{0.f, -sx}, {cx, 0.f}}};
    c32 RY[2][2] = {{{cy, 0.f}, {-sy, 0.f}}, {{sy, 0.f}, {cy, 0.f}}};
    c32 RZ[2][2] = {{{cz, -sz}, {0.f, 0.f}}, {{0.f, 0.f}, {cz, sz}}};
    c32 T[2][2];
    mm2(RY, RX, T);
    mm2(RZ, T, U);
}
__device__ void kron22(const c32 A[2][2], const c32 B[2][2], c32 K[4][4]) {
    for (int i = 0; i < 2; i++)
        for (int j = 0; j < 2; j++)
            for (int k = 0; k < 2; k++)
                for (int l = 0; l < 2; l++)
                    K[i * 2 + j][k * 2 + l] = cmul(A[i][k], B[j][l]);
}

// Build the 19 fused 4x4 staircase gates.
// G_q = Post_q * M_q * Pre_q  acting on qubits (q, q+1); applied in order q = 0..18.
// Pre_0 = U_0 (x) U_1 ; Pre_q = I (x) U_{q+1}
// Post_18 = V_18 (x) V_19 ; Post_q = V_q (x) I
__global__ void build_gates(const float* __restrict__ w, c32* __restrict__ G) {
    int q = threadIdx.x;
    if (q >= NGATES) return;
    const float WM = 0.63245553203367586640f;
    float hx = w[60 + 3 * q] * WM * 0.5f;
    float hy = w[61 + 3 * q] * WM * 0.5f;
    float hz = w[62 + 3 * q] * WM * 0.5f;
    float cx = cosf(hx), sx = sinf(hx);
    float cy = cosf(hy), sy = sinf(hy);
    float cz = cosf(hz), sz = sinf(hz);
    c32 RXX[4][4], RYY[4][4], RZZ[4][4];
    for (int i = 0; i < 4; i++)
        for (int j = 0; j < 4; j++) {
            RXX[i][j] = make_float2(0.f, 0.f);
            RYY[i][j] = make_float2(0.f, 0.f);
            RZZ[i][j] = make_float2(0.f, 0.f);
        }
    for (int i = 0; i < 4; i++) {
        RXX[i][i]     = make_float2(cx, 0.f);
        RXX[i][3 - i] = make_float2(0.f, -sx);
        RYY[i][i]     = make_float2(cy, 0.f);
    }
    RYY[0][3] = make_float2(0.f,  sy);
    RYY[1][2] = make_float2(0.f, -sy);
    RYY[2][1] = make_float2(0.f, -sy);
    RYY[3][0] = make_float2(0.f,  sy);
    RZZ[0][0] = make_float2(cz, -sz);
    RZZ[1][1] = make_float2(cz,  sz);
    RZZ[2][2] = make_float2(cz,  sz);
    RZZ[3][3] = make_float2(cz, -sz);
    c32 T[4][4], M[4][4];
    mm4(RYY, RXX, T);
    mm4(RZZ, T, M);

    c32 I2[2][2] = {{{1.f, 0.f}, {0.f, 0.f}}, {{0.f, 0.f}, {1.f, 0.f}}};
    c32 Ua[2][2], Ub[2][2], Pre[4][4], Post[4][4];
    if (q == 0) {
        single_u(w, 0, Ua);
        single_u(w, 3, Ub);
        kron22(Ua, Ub, Pre);
    } else {
        single_u(w, 3 * (q + 1), Ub);
        kron22(I2, Ub, Pre);
    }
    if (q == NGATES - 1) {
        single_u(w, L2OFF + 3 * 18, Ua);
        single_u(w, L2OFF + 3 * 19, Ub);
        kron22(Ua, Ub, Post);
    } else {
        single_u(w, L2OFF + 3 * q, Ua);
        kron22(Ua, I2, Post);
    }
    c32 T2[4][4], Gq[4][4];
    mm4(M, Pre, T2);
    mm4(Post, T2, Gq);
    for (int i = 0; i < 4; i++)
        for (int j = 0; j < 4; j++)
            G[q * 16 + i * 4 + j] = Gq[i][j];
}

// Gate 0 (qubits 0,1 <-> bits 19,18), reading the real input x, writing psi.
__global__ __launch_bounds__(256) void apply_gate0(const float* __restrict__ x,
                                                   c32* __restrict__ psi,
                                                   const c32* __restrict__ Gall) {
    c32 g[16];
#pragma unroll
    for (int k = 0; k < 16; k++) g[k] = Gall[k];
    unsigned tid = blockIdx.x * 256u + threadIdx.x;  // 0 .. 2^20-1
    unsigned b = tid >> 18;
    unsigned t = tid & 0x3FFFFu;          // low 18 bits; group = top-2 bits
    unsigned base = (b << 20) + t;
    const unsigned s = 1u << 18;
    float a0 = x[base], a1 = x[base + s], a2 = x[base + 2 * s], a3 = x[base + 3 * s];
#pragma unroll
    for (int i = 0; i < 4; i++) {
        c32 r = make_float2(g[i * 4 + 0].x * a0 + g[i * 4 + 1].x * a1 + g[i * 4 + 2].x * a2 + g[i * 4 + 3].x * a3,
                            g[i * 4 + 0].y * a0 + g[i * 4 + 1].y * a1 + g[i * 4 + 2].y * a2 + g[i * 4 + 3].y * a3);
        psi[base + (unsigned)i * s] = r;
    }
}

// In-place 4x4 gate on adjacent bits (b1,b0) = (19-q, 18-q).
__global__ __launch_bounds__(256) void apply_gate(c32* __restrict__ psi,
                                                  const c32* __restrict__ Gall, int gq) {
    const int b0 = 18 - gq;
    const c32* Gp = Gall + gq * 16;
    c32 g[16];
#pragma unroll
    for (int k = 0; k < 16; k++) g[k] = Gp[k];
    unsigned tid = blockIdx.x * 256u + threadIdx.x;  // 0 .. 2^20-1
    unsigned b = tid >> 18;
    unsigned t = tid & 0x3FFFFu;
    unsigned low = t & ((1u << b0) - 1u);
    unsigned high = t >> b0;
    unsigned base = (b << 20) + (high << (b0 + 2)) + low;
    unsigned s = 1u << b0;
    c32 a0 = psi[base], a1 = psi[base + s], a2 = psi[base + 2 * s], a3 = psi[base + 3 * s];
    c32 r0 = make_float2(0.f, 0.f), r1 = r0, r2 = r0, r3 = r0;
    r0 = cmadd(cmadd(cmadd(cmadd(r0, g[0],  a0), g[1],  a1), g[2],  a2), g[3],  a3);
    r1 = cmadd(cmadd(cmadd(cmadd(r1, g[4],  a0), g[5],  a1), g[6],  a2), g[7],  a3);
    r2 = cmadd(cmadd(cmadd(cmadd(r2, g[8],  a0), g[9],  a1), g[10], a2), g[11], a3);
    r3 = cmadd(cmadd(cmadd(cmadd(r3, g[12], a0), g[13], a1), g[14], a2), g[15], a3);
    psi[base] = r0;
    psi[base + s] = r1;
    psi[base + 2 * s] = r2;
    psi[base + 3 * s] = r3;
}

// rdm[b,a,c] = sum_t psi[b,t,a] * conj(psi[b,t,c]); Hermitian -> upper-tri tiles + mirror.
// Block: 64x64 output tile, 256 threads as 16x16, each 4x4 complex accumulators.
__global__ __launch_bounds__(256) void gram(const c32* __restrict__ psi, float2* __restrict__ out) {
    __shared__ c32 At[16][65];
    __shared__ c32 Ct[16][65];
    int b = blockIdx.y;
    // triangular decode: 136 tiles, ia <= ic
    int rem = blockIdx.x;
    int ia = 0;
    while (rem >= 16 - ia) { rem -= 16 - ia; ++ia; }
    int ic = ia + rem;
    int a0 = ia * 64, c0 = ic * 64;
    int tx = threadIdx.x & 15, ty = threadIdx.x >> 4;
    float accr[4][4] = {}, acci[4][4] = {};
    const c32* P = psi + ((size_t)b << 20);
    for (int tch = 0; tch < 1024; tch += 16) {
        int e = threadIdx.x * 2;
        int r1 = e >> 6, col = e & 63;
        int r2 = r1 + 8;
        float4 va1 = *reinterpret_cast<const float4*>(P + (size_t)(tch + r1) * 1024 + a0 + col);
        float4 va2 = *reinterpret_cast<const float4*>(P + (size_t)(tch + r2) * 1024 + a0 + col);
        float4 vc1 = *reinterpret_cast<const float4*>(P + (size_t)(tch + r1) * 1024 + c0 + col);
        float4 vc2 = *reinterpret_cast<const float4*>(P + (size_t)(tch + r2) * 1024 + c0 + col);
        At[r1][col] = make_float2(va1.x, va1.y);
        At[r1][col + 1] = make_float2(va1.z, va1.w);
        At[r2][col] = make_float2(va2.x, va2.y);
        At[r2][col + 1] = make_float2(va2.z, va2.w);
        Ct[r1][col] = make_float2(vc1.x, vc1.y);
        Ct[r1][col + 1] = make_float2(vc1.z, vc1.w);
        Ct[r2][col] = make_float2(vc2.x, vc2.y);
        Ct[r2][col + 1] = make_float2(vc2.z, vc2.w);
        __syncthreads();
#pragma unroll
        for (int tt = 0; tt < 16; ++tt) {
            c32 av[4], cv[4];
#pragma unroll
            for (int i = 0; i < 4; i++) av[i] = At[tt][ty * 4 + i];
#pragma unroll
            for (int j = 0; j < 4; j++) cv[j] = Ct[tt][tx * 4 + j];
#pragma unroll
            for (int i = 0; i < 4; i++)
#pragma unroll
                for (int j = 0; j < 4; j++) {
                    accr[i][j] = fmaf(av[i].x, cv[j].x, fmaf(av[i].y, cv[j].y, accr[i][j]));
                    acci[i][j] = fmaf(av[i].y, cv[j].x, fmaf(-av[i].x, cv[j].y, acci[i][j]));
                }
        }
        __syncthreads();
    }
    size_t ob = (size_t)b << 20;
#pragma unroll
    for (int i = 0; i < 4; i++) {
        int a = a0 + ty * 4 + i;
#pragma unroll
        for (int j = 0; j < 4; j++) {
            int c = c0 + tx * 4 + j;
            out[ob + ((size_t)a << 10) + c] = make_float2(accr[i][j], acci[i][j]);
        }
    }
    if (ia != ic) {
#pragma unroll
        for (int i = 0; i < 4; i++) {
            int a = a0 + ty * 4 + i;
#pragma unroll
            for (int j = 0; j < 4; j++) {
                int c = c0 + tx * 4 + j;
                out[ob + ((size_t)c << 10) + a] = make_float2(accr[i][j], -acci[i][j]);
            }
        }
    }
}

extern "C" void kernel_launch(void* const* d_in, const int* in_sizes, int n_in,
                              void* d_out, int out_size, void* d_ws, size_t ws_size,
                              hipStream_t stream) {
    const float* x = (const float*)d_in[0];
    const float* weight = (const float*)d_in[1];
    c32* psi = (c32*)d_ws;                                   // 4 * 2^20 complex = 32 MB
    c32* G = (c32*)((char*)d_ws + (size_t)BATCH * DIM * sizeof(c32));  // 19*16 complex

    build_gates<<<1, 64, 0, stream>>>(weight, G);
    apply_gate0<<<(BATCH * DIM / 4) / 256, 256, 0, stream>>>(x, psi, G);
    for (int q = 1; q < NGATES; ++q)
        apply_gate<<<(BATCH * DIM / 4) / 256, 256, 0, stream>>>(psi, G, q);
    gram<<<dim3(136, BATCH), 256, 0, stream>>>(psi, (float2*)d_out);
}

// Round 2
// 171.499 us; speedup vs baseline: 3.0504x; 3.0504x over previous
//
#include <hip/hip_runtime.h>
#include <hip/hip_bf16.h>

#define N_Q    20
#define DIM    (1 << N_Q)      // 1048576
#define BATCH  4
#define NGATES 19
#define L2OFF  117             // 6n-3 : second xyz layer offset

typedef float2 c32;
typedef __attribute__((ext_vector_type(8))) short short8;
typedef __attribute__((ext_vector_type(4))) float f32x4;

__device__ __forceinline__ c32 cmul(c32 a, c32 b) {
    return make_float2(fmaf(a.x, b.x, -a.y * b.y), fmaf(a.x, b.y, a.y * b.x));
}
__device__ __forceinline__ c32 cmadd(c32 acc, c32 a, c32 b) {
    acc.x = fmaf(a.x, b.x, fmaf(-a.y, b.y, acc.x));
    acc.y = fmaf(a.x, b.y, fmaf(a.y, b.x, acc.y));
    return acc;
}
__device__ __forceinline__ unsigned short f2bf(float f) {
    union { float f; unsigned u; } v; v.f = f;
    unsigned r = v.u + 0x7FFFu + ((v.u >> 16) & 1u);
    return (unsigned short)(r >> 16);
}

__device__ void mm2(const c32 A[2][2], const c32 B[2][2], c32 C[2][2]) {
    for (int i = 0; i < 2; i++)
        for (int j = 0; j < 2; j++) {
            c32 s = make_float2(0.f, 0.f);
            for (int k = 0; k < 2; k++) s = cmadd(s, A[i][k], B[k][j]);
            C[i][j] = s;
        }
}
__device__ void mm4(const c32 A[4][4], const c32 B[4][4], c32 C[4][4]) {
    for (int i = 0; i < 4; i++)
        for (int j = 0; j < 4; j++) {
            c32 s = make_float2(0.f, 0.f);
            for (int k = 0; k < 4; k++) s = cmadd(s, A[i][k], B[k][j]);
            C[i][j] = s;
        }
}
__device__ void single_u(const float* w, int base, c32 U[2][2]) {
    const float WM = 0.63245553203367586640f;  // sqrt(2/5)
    float hx = w[base] * WM * 0.5f, hy = w[base + 1] * WM * 0.5f, hz = w[base + 2] * WM * 0.5f;
    float cx = cosf(hx), sx = sinf(hx);
    float cy = cosf(hy), sy = sinf(hy);
    float cz = cosf(hz), sz = sinf(hz);
    c32 RX[2][2] = {{{cx, 0.f}, {0.f, -sx}}, {{0.f, -sx}, {cx, 0.f}}};
    c32 RY[2][2] = {{{cy, 0.f}, {-sy, 0.f}}, {{sy, 0.f}, {cy, 0.f}}};
    c32 RZ[2][2] = {{{cz, -sz}, {0.f, 0.f}}, {{0.f, 0.f}, {cz, sz}}};
    c32 T[2][2];
    mm2(RY, RX, T);
    mm2(RZ, T, U);
}
__device__ void kron22(const c32 A[2][2], const c32 B[2][2], c32 K[4][4]) {
    for (int i = 0; i < 2; i++)
        for (int j = 0; j < 2; j++)
            for (int k = 0; k < 2; k++)
                for (int l = 0; l < 2; l++)
                    K[i * 2 + j][k * 2 + l] = cmul(A[i][k], B[j][l]);
}

// Build the 19 fused 4x4 staircase gates (see round-0 derivation).
__global__ void build_gates(const float* __restrict__ w, c32* __restrict__ G) {
    int q = threadIdx.x;
    if (q >= NGATES) return;
    const float WM = 0.63245553203367586640f;
    float hx = w[60 + 3 * q] * WM * 0.5f;
    float hy = w[61 + 3 * q] * WM * 0.5f;
    float hz = w[62 + 3 * q] * WM * 0.5f;
    float cx = cosf(hx), sx = sinf(hx);
    float cy = cosf(hy), sy = sinf(hy);
    float cz = cosf(hz), sz = sinf(hz);
    c32 RXX[4][4], RYY[4][4], RZZ[4][4];
    for (int i = 0; i < 4; i++)
        for (int j = 0; j < 4; j++) {
            RXX[i][j] = make_float2(0.f, 0.f);
            RYY[i][j] = make_float2(0.f, 0.f);
            RZZ[i][j] = make_float2(0.f, 0.f);
        }
    for (int i = 0; i < 4; i++) {
        RXX[i][i]     = make_float2(cx, 0.f);
        RXX[i][3 - i] = make_float2(0.f, -sx);
        RYY[i][i]     = make_float2(cy, 0.f);
    }
    RYY[0][3] = make_float2(0.f,  sy);
    RYY[1][2] = make_float2(0.f, -sy);
    RYY[2][1] = make_float2(0.f, -sy);
    RYY[3][0] = make_float2(0.f,  sy);
    RZZ[0][0] = make_float2(cz, -sz);
    RZZ[1][1] = make_float2(cz,  sz);
    RZZ[2][2] = make_float2(cz,  sz);
    RZZ[3][3] = make_float2(cz, -sz);
    c32 T[4][4], M[4][4];
    mm4(RYY, RXX, T);
    mm4(RZZ, T, M);

    c32 I2m[2][2] = {{{1.f, 0.f}, {0.f, 0.f}}, {{0.f, 0.f}, {1.f, 0.f}}};
    c32 Ua[2][2], Ub[2][2], Pre[4][4], Post[4][4];
    if (q == 0) {
        single_u(w, 0, Ua);
        single_u(w, 3, Ub);
        kron22(Ua, Ub, Pre);
    } else {
        single_u(w, 3 * (q + 1), Ub);
        kron22(I2m, Ub, Pre);
    }
    if (q == NGATES - 1) {
        single_u(w, L2OFF + 3 * 18, Ua);
        single_u(w, L2OFF + 3 * 19, Ub);
        kron22(Ua, Ub, Post);
    } else {
        single_u(w, L2OFF + 3 * q, Ua);
        kron22(Ua, I2m, Post);
    }
    c32 T2[4][4], Gq[4][4];
    mm4(M, Pre, T2);
    mm4(Post, T2, Gq);
    for (int i = 0; i < 4; i++)
        for (int j = 0; j < 4; j++)
            G[q * 16 + i * 4 + j] = Gq[i][j];
}

// Gate 0 (qubits 0,1 <-> bits 19,18), reading the real input x, writing psi.
__global__ __launch_bounds__(256) void apply_gate0(const float* __restrict__ x,
                                                   c32* __restrict__ psi,
                                                   const c32* __restrict__ Gall) {
    c32 g[16];
#pragma unroll
    for (int k = 0; k < 16; k++) g[k] = Gall[k];
    unsigned tid = blockIdx.x * 256u + threadIdx.x;  // 0 .. 2^20-1
    unsigned b = tid >> 18;
    unsigned t = tid & 0x3FFFFu;
    unsigned base = (b << 20) + t;
    const unsigned s = 1u << 18;
    float a0 = x[base], a1 = x[base + s], a2 = x[base + 2 * s], a3 = x[base + 3 * s];
#pragma unroll
    for (int i = 0; i < 4; i++) {
        c32 r = make_float2(g[i * 4 + 0].x * a0 + g[i * 4 + 1].x * a1 + g[i * 4 + 2].x * a2 + g[i * 4 + 3].x * a3,
                            g[i * 4 + 0].y * a0 + g[i * 4 + 1].y * a1 + g[i * 4 + 2].y * a2 + g[i * 4 + 3].y * a3);
        psi[base + (unsigned)i * s] = r;
    }
}

__device__ __forceinline__ void apply4(const c32* g, c32& x0, c32& x1, c32& x2, c32& x3) {
    c32 r0 = cmul(g[0],  x0); r0 = cmadd(r0, g[1],  x1); r0 = cmadd(r0, g[2],  x2); r0 = cmadd(r0, g[3],  x3);
    c32 r1 = cmul(g[4],  x0); r1 = cmadd(r1, g[5],  x1); r1 = cmadd(r1, g[6],  x2); r1 = cmadd(r1, g[7],  x3);
    c32 r2 = cmul(g[8],  x0); r2 = cmadd(r2, g[9],  x1); r2 = cmadd(r2, g[10], x2); r2 = cmadd(r2, g[11], x3);
    c32 r3 = cmul(g[12], x0); r3 = cmadd(r3, g[13], x1); r3 = cmadd(r3, g[14], x2); r3 = cmadd(r3, g[15], x3);
    x0 = r0; x1 = r1; x2 = r2; x3 = r3;
}

// Apply gates q and q+1 in one pass. Gate q acts on bits (19-q, 18-q),
// gate q+1 on (18-q, 17-q). Each thread owns the 8 amplitudes spanning
// bits (lo+2, lo+1, lo), lo = 17-q, and applies both 4x4s in-register.
__global__ __launch_bounds__(256) void apply_gate_pair(c32* __restrict__ psi,
                                                       const c32* __restrict__ Gall, int q) {
    const int lo = 17 - q;
    const c32* G0 = Gall + q * 16;
    const c32* G1 = Gall + (q + 1) * 16;
    c32 g0[16], g1[16];
#pragma unroll
    for (int k = 0; k < 16; k++) { g0[k] = G0[k]; g1[k] = G1[k]; }
    unsigned tid = blockIdx.x * 256u + threadIdx.x;  // 0 .. 2^19-1
    unsigned b = tid >> 17;
    unsigned t = tid & 0x1FFFFu;
    unsigned low = t & ((1u << lo) - 1u);
    unsigned high = t >> lo;
    unsigned base = (b << 20) + (high << (lo + 3)) + low;
    c32 a[8];
#pragma unroll
    for (int j = 0; j < 8; j++) a[j] = psi[base + ((unsigned)j << lo)];
    // G_q on bits (hi,mid): vectors {a[v],a[2+v],a[4+v],a[6+v]}, v = bit lo value
    apply4(g0, a[0], a[2], a[4], a[6]);
    apply4(g0, a[1], a[3], a[5], a[7]);
    // G_{q+1} on bits (mid,lo): vectors {a[4h+0..3]}, h = bit hi value
    apply4(g1, a[0], a[1], a[2], a[3]);
    apply4(g1, a[4], a[5], a[6], a[7]);
#pragma unroll
    for (int j = 0; j < 8; j++) psi[base + ((unsigned)j << lo)] = a[j];
}

// Transpose + bf16 cast: psi[b][t][a] c32 -> Art[b][a][t], Ait[b][a][t] bf16.
// 64x64 tiles; phase 1 coalesced read along a, phase 2 coalesced write along t.
__global__ __launch_bounds__(256) void conv_transpose(const c32* __restrict__ psi,
                                                      unsigned short* __restrict__ Art,
                                                      unsigned short* __restrict__ Ait) {
    __shared__ c32 lds[64][65];
    int b  = blockIdx.z;
    int t0 = blockIdx.x * 64;
    int a0 = blockIdx.y * 64;
    const c32* P = psi + ((size_t)b << 20);
#pragma unroll
    for (int p = 0; p < 8; ++p) {
        int idx = threadIdx.x + p * 256;        // float4 index, 2048 total
        int t = idx >> 5;                        // 32 float4 per row
        int a2 = (idx & 31) * 2;
        float4 v = *reinterpret_cast<const float4*>(P + ((size_t)(t0 + t) << 10) + a0 + a2);
        lds[t][a2]     = make_float2(v.x, v.y);
        lds[t][a2 + 1] = make_float2(v.z, v.w);
    }
    __syncthreads();
#pragma unroll
    for (int p = 0; p < 2; ++p) {
        int idx = threadIdx.x + p * 256;        // 512 tasks: (a, t-chunk of 8)
        int a = idx >> 3;
        int tc = (idx & 7) * 8;
        unsigned short rr[8], ri[8];
#pragma unroll
        for (int i = 0; i < 8; ++i) {
            c32 v = lds[tc + i][a];
            rr[i] = f2bf(v.x);
            ri[i] = f2bf(v.y);
        }
        size_t o = ((size_t)b << 20) + ((size_t)(a0 + a) << 10) + t0 + tc;
        *reinterpret_cast<float4*>(Art + o) = *reinterpret_cast<float4*>(rr);
        *reinterpret_cast<float4*>(Ait + o) = *reinterpret_cast<float4*>(ri);
    }
}

// MFMA Gram: rdm[a,c] = sum_t psi[t,a]*conj(psi[t,c])
//  Re = Ar.Ar^T + Ai.Ai^T (symmetric), Im = Ai.Ar^T - Ar.Ai^T (antisymmetric)
// with Ar/Ai stored transposed [a][t] bf16 row-major (gemm_bt pattern).
// 64x64 tile per block, BK=64, 4 waves as 2x2 each 32x32, 3 acc sets.
#define LDP 72  // padded LDS row (bf16 elems): 144 B stride -> uniform bank stripes
__global__ __launch_bounds__(256) void gram_mfma(const unsigned short* __restrict__ Art,
                                                 const unsigned short* __restrict__ Ait,
                                                 float2* __restrict__ out) {
    __shared__ unsigned short ldsRr[64 * LDP], ldsRi[64 * LDP];
    __shared__ unsigned short ldsCr[64 * LDP], ldsCi[64 * LDP];
    int b = blockIdx.y;
    int rem = blockIdx.x;                        // triangular decode, ia <= ic
    int ia = 0;
    while (rem >= 16 - ia) { rem -= 16 - ia; ++ia; }
    int ic = ia + rem;
    int a0 = ia * 64, c0 = ic * 64;

    int lane = threadIdx.x & 63;
    int w = threadIdx.x >> 6;
    int wr = (w >> 1) * 32, wc = (w & 1) * 32;
    int lrow = lane & 15;
    int lk   = (lane >> 4) * 8;

    f32x4 accS[2][2], accP1[2][2], accP2[2][2];
#pragma unroll
    for (int m = 0; m < 2; m++)
#pragma unroll
        for (int n = 0; n < 2; n++) {
            accS[m][n] = (f32x4)0.f; accP1[m][n] = (f32x4)0.f; accP2[m][n] = (f32x4)0.f;
        }

    size_t gb = (size_t)b << 20;
    for (int k0 = 0; k0 < 1024; k0 += 64) {
        __syncthreads();
#pragma unroll
        for (int s = 0; s < 2; ++s) {
            int cchunk = threadIdx.x + s * 256;  // 512 chunks of 16 B per tile
            int row = cchunk >> 3;
            int col = (cchunk & 7) * 8;
            size_t gR = gb + ((size_t)(a0 + row) << 10) + k0 + col;
            size_t gC = gb + ((size_t)(c0 + row) << 10) + k0 + col;
            float4 vRr = *reinterpret_cast<const float4*>(Art + gR);
            float4 vRi = *reinterpret_cast<const float4*>(Ait + gR);
            float4 vCr = *reinterpret_cast<const float4*>(Art + gC);
            float4 vCi = *reinterpret_cast<const float4*>(Ait + gC);
            int la = row * LDP + col;
            *reinterpret_cast<float4*>(ldsRr + la) = vRr;
            *reinterpret_cast<float4*>(ldsRi + la) = vRi;
            *reinterpret_cast<float4*>(ldsCr + la) = vCr;
            *reinterpret_cast<float4*>(ldsCi + la) = vCi;
        }
        __syncthreads();
#pragma unroll
        for (int kk = 0; kk < 2; ++kk) {
            int ko = kk * 32 + lk;
            short8 ar[2], ai[2], br[2], bi[2];
#pragma unroll
            for (int m = 0; m < 2; m++) {
                int r = (wr + m * 16 + lrow) * LDP + ko;
                ar[m] = *reinterpret_cast<const short8*>(ldsRr + r);
                ai[m] = *reinterpret_cast<const short8*>(ldsRi + r);
            }
#pragma unroll
            for (int n = 0; n < 2; n++) {
                int r = (wc + n * 16 + lrow) * LDP + ko;
                br[n] = *reinterpret_cast<const short8*>(ldsCr + r);
                bi[n] = *reinterpret_cast<const short8*>(ldsCi + r);
            }
#pragma unroll
            for (int m = 0; m < 2; m++)
#pragma unroll
                for (int n = 0; n < 2; n++) {
                    accS[m][n]  = __builtin_amdgcn_mfma_f32_16x16x32_bf16(ar[m], br[n], accS[m][n], 0, 0, 0);
                    accS[m][n]  = __builtin_amdgcn_mfma_f32_16x16x32_bf16(ai[m], bi[n], accS[m][n], 0, 0, 0);
                    accP1[m][n] = __builtin_amdgcn_mfma_f32_16x16x32_bf16(ai[m], br[n], accP1[m][n], 0, 0, 0);
                    accP2[m][n] = __builtin_amdgcn_mfma_f32_16x16x32_bf16(ar[m], bi[n], accP2[m][n], 0, 0, 0);
                }
        }
    }
    // C/D layout: col = lane&15, row = (lane>>4)*4 + reg  [m89/m91 verified]
    size_t ob = (size_t)b << 20;
#pragma unroll
    for (int m = 0; m < 2; m++)
#pragma unroll
        for (int n = 0; n < 2; n++)
#pragma unroll
            for (int r = 0; r < 4; r++) {
                int a = a0 + wr + m * 16 + (lane >> 4) * 4 + r;
                int c = c0 + wc + n * 16 + (lane & 15);
                float re = accS[m][n][r];
                float im = accP1[m][n][r] - accP2[m][n][r];
                out[ob + ((size_t)a << 10) + c] = make_float2(re, im);
                if (ia != ic)
                    out[ob + ((size_t)c << 10) + a] = make_float2(re, -im);
            }
}

// fp32 fallback gram (round-0), used only if ws_size can't hold Art/Ait.
__global__ __launch_bounds__(256) void gram_f32(const c32* __restrict__ psi, float2* __restrict__ out) {
    __shared__ c32 At[16][65];
    __shared__ c32 Ct[16][65];
    int b = blockIdx.y;
    int rem = blockIdx.x;
    int ia = 0;
    while (rem >= 16 - ia) { rem -= 16 - ia; ++ia; }
    int ic = ia + rem;
    int a0 = ia * 64, c0 = ic * 64;
    int tx = threadIdx.x & 15, ty = threadIdx.x >> 4;
    float accr[4][4] = {}, acci[4][4] = {};
    const c32* P = psi + ((size_t)b << 20);
    for (int tch = 0; tch < 1024; tch += 16) {
        int e = threadIdx.x * 2;
        int r1 = e >> 6, col = e & 63;
        int r2 = r1 + 8;
        float4 va1 = *reinterpret_cast<const float4*>(P + (size_t)(tch + r1) * 1024 + a0 + col);
        float4 va2 = *reinterpret_cast<const float4*>(P + (size_t)(tch + r2) * 1024 + a0 + col);
        float4 vc1 = *reinterpret_cast<const float4*>(P + (size_t)(tch + r1) * 1024 + c0 + col);
        float4 vc2 = *reinterpret_cast<const float4*>(P + (size_t)(tch + r2) * 1024 + c0 + col);
        At[r1][col] = make_float2(va1.x, va1.y);
        At[r1][col + 1] = make_float2(va1.z, va1.w);
        At[r2][col] = make_float2(va2.x, va2.y);
        At[r2][col + 1] = make_float2(va2.z, va2.w);
        Ct[r1][col] = make_float2(vc1.x, vc1.y);
        Ct[r1][col + 1] = make_float2(vc1.z, vc1.w);
        Ct[r2][col] = make_float2(vc2.x, vc2.y);
        Ct[r2][col + 1] = make_float2(vc2.z, vc2.w);
        __syncthreads();
#pragma unroll
        for (int tt = 0; tt < 16; ++tt) {
            c32 av[4], cv[4];
#pragma unroll
            for (int i = 0; i < 4; i++) av[i] = At[tt][ty * 4 + i];
#pragma unroll
            for (int j = 0; j < 4; j++) cv[j] = Ct[tt][tx * 4 + j];
#pragma unroll
            for (int i = 0; i < 4; i++)
#pragma unroll
                for (int j = 0; j < 4; j++) {
                    accr[i][j] = fmaf(av[i].x, cv[j].x, fmaf(av[i].y, cv[j].y, accr[i][j]));
                    acci[i][j] = fmaf(av[i].y, cv[j].x, fmaf(-av[i].x, cv[j].y, acci[i][j]));
                }
        }
        __syncthreads();
    }
    size_t ob = (size_t)b << 20;
#pragma unroll
    for (int i = 0; i < 4; i++) {
        int a = a0 + ty * 4 + i;
#pragma unroll
        for (int j = 0; j < 4; j++) {
            int c = c0 + tx * 4 + j;
            out[ob + ((size_t)a << 10) + c] = make_float2(accr[i][j], acci[i][j]);
        }
    }
    if (ia != ic) {
#pragma unroll
        for (int i = 0; i < 4; i++) {
            int a = a0 + ty * 4 + i;
#pragma unroll
            for (int j = 0; j < 4; j++) {
                int c = c0 + tx * 4 + j;
                out[ob + ((size_t)c << 10) + a] = make_float2(accr[i][j], -acci[i][j]);
            }
        }
    }
}

extern "C" void kernel_launch(void* const* d_in, const int* in_sizes, int n_in,
                              void* d_out, int out_size, void* d_ws, size_t ws_size,
                              hipStream_t stream) {
    const float* x = (const float*)d_in[0];
    const float* weight = (const float*)d_in[1];
    const size_t psiBytes = (size_t)BATCH * DIM * sizeof(c32);       // 32 MB
    c32* psi = (c32*)d_ws;
    c32* G = (c32*)((char*)d_ws + psiBytes);
    unsigned short* Art = (unsigned short*)((char*)d_ws + psiBytes + 65536);
    unsigned short* Ait = Art + (size_t)BATCH * DIM;                 // 8 MB each
    const size_t needed = psiBytes + 65536 + 2 * (size_t)BATCH * DIM * sizeof(unsigned short);

    build_gates<<<1, 64, 0, stream>>>(weight, G);
    apply_gate0<<<(BATCH * DIM / 4) / 256, 256, 0, stream>>>(x, psi, G);
    for (int q = 1; q < NGATES; q += 2)
        apply_gate_pair<<<(BATCH * DIM / 8) / 256, 256, 0, stream>>>(psi, G, q);

    if (ws_size >= needed) {
        conv_transpose<<<dim3(16, 16, BATCH), 256, 0, stream>>>(psi, Art, Ait);
        gram_mfma<<<dim3(136, BATCH), 256, 0, stream>>>(Art, Ait, (float2*)d_out);
    } else {
        gram_f32<<<dim3(136, BATCH), 256, 0, stream>>>(psi, (float2*)d_out);
    }
}

// Round 3
// 115.063 us; speedup vs baseline: 4.5465x; 1.4905x over previous
//
#include <hip/hip_runtime.h>
#include <hip/hip_bf16.h>

#define N_Q    20
#define DIM    (1 << N_Q)      // 1048576
#define BATCH  4
#define NGATES 19
#define L2OFF  117             // 6n-3 : second xyz layer offset

typedef float2 c32;
typedef __attribute__((ext_vector_type(8))) short short8;
typedef __attribute__((ext_vector_type(4))) float f32x4;

__device__ __forceinline__ c32 cmul(c32 a, c32 b) {
    return make_float2(fmaf(a.x, b.x, -a.y * b.y), fmaf(a.x, b.y, a.y * b.x));
}
__device__ __forceinline__ c32 cmadd(c32 acc, c32 a, c32 b) {
    acc.x = fmaf(a.x, b.x, fmaf(-a.y, b.y, acc.x));
    acc.y = fmaf(a.x, b.y, fmaf(a.y, b.x, acc.y));
    return acc;
}
__device__ __forceinline__ unsigned short f2bf(float f) {
    union { float f; unsigned u; } v; v.f = f;
    unsigned r = v.u + 0x7FFFu + ((v.u >> 16) & 1u);
    return (unsigned short)(r >> 16);
}

__device__ void mm2(const c32 A[2][2], const c32 B[2][2], c32 C[2][2]) {
    for (int i = 0; i < 2; i++)
        for (int j = 0; j < 2; j++) {
            c32 s = make_float2(0.f, 0.f);
            for (int k = 0; k < 2; k++) s = cmadd(s, A[i][k], B[k][j]);
            C[i][j] = s;
        }
}
__device__ void mm4(const c32 A[4][4], const c32 B[4][4], c32 C[4][4]) {
    for (int i = 0; i < 4; i++)
        for (int j = 0; j < 4; j++) {
            c32 s = make_float2(0.f, 0.f);
            for (int k = 0; k < 4; k++) s = cmadd(s, A[i][k], B[k][j]);
            C[i][j] = s;
        }
}
__device__ void single_u(const float* w, int base, c32 U[2][2]) {
    const float WM = 0.63245553203367586640f;  // sqrt(2/5)
    float hx = w[base] * WM * 0.5f, hy = w[base + 1] * WM * 0.5f, hz = w[base + 2] * WM * 0.5f;
    float cx = cosf(hx), sx = sinf(hx);
    float cy = cosf(hy), sy = sinf(hy);
    float cz = cosf(hz), sz = sinf(hz);
    c32 RX[2][2] = {{{cx, 0.f}, {0.f, -sx}}, {{0.f, -sx}, {cx, 0.f}}};
    c32 RY[2][2] = {{{cy, 0.f}, {-sy, 0.f}}, {{sy, 0.f}, {cy, 0.f}}};
    c32 RZ[2][2] = {{{cz, -sz}, {0.f, 0.f}}, {{0.f, 0.f}, {cz, sz}}};
    c32 T[2][2];
    mm2(RY, RX, T);
    mm2(RZ, T, U);
}
__device__ void kron22(const c32 A[2][2], const c32 B[2][2], c32 K[4][4]) {
    for (int i = 0; i < 2; i++)
        for (int j = 0; j < 2; j++)
            for (int k = 0; k < 2; k++)
                for (int l = 0; l < 2; l++)
                    K[i * 2 + j][k * 2 + l] = cmul(A[i][k], B[j][l]);
}

// Build the 19 fused 4x4 staircase gates (round-0 derivation).
__global__ void build_gates(const float* __restrict__ w, c32* __restrict__ G) {
    int q = threadIdx.x;
    if (q >= NGATES) return;
    const float WM = 0.63245553203367586640f;
    float hx = w[60 + 3 * q] * WM * 0.5f;
    float hy = w[61 + 3 * q] * WM * 0.5f;
    float hz = w[62 + 3 * q] * WM * 0.5f;
    float cx = cosf(hx), sx = sinf(hx);
    float cy = cosf(hy), sy = sinf(hy);
    float cz = cosf(hz), sz = sinf(hz);
    c32 RXX[4][4], RYY[4][4], RZZ[4][4];
    for (int i = 0; i < 4; i++)
        for (int j = 0; j < 4; j++) {
            RXX[i][j] = make_float2(0.f, 0.f);
            RYY[i][j] = make_float2(0.f, 0.f);
            RZZ[i][j] = make_float2(0.f, 0.f);
        }
    for (int i = 0; i < 4; i++) {
        RXX[i][i]     = make_float2(cx, 0.f);
        RXX[i][3 - i] = make_float2(0.f, -sx);
        RYY[i][i]     = make_float2(cy, 0.f);
    }
    RYY[0][3] = make_float2(0.f,  sy);
    RYY[1][2] = make_float2(0.f, -sy);
    RYY[2][1] = make_float2(0.f, -sy);
    RYY[3][0] = make_float2(0.f,  sy);
    RZZ[0][0] = make_float2(cz, -sz);
    RZZ[1][1] = make_float2(cz,  sz);
    RZZ[2][2] = make_float2(cz,  sz);
    RZZ[3][3] = make_float2(cz, -sz);
    c32 T[4][4], M[4][4];
    mm4(RYY, RXX, T);
    mm4(RZZ, T, M);

    c32 I2m[2][2] = {{{1.f, 0.f}, {0.f, 0.f}}, {{0.f, 0.f}, {1.f, 0.f}}};
    c32 Ua[2][2], Ub[2][2], Pre[4][4], Post[4][4];
    if (q == 0) {
        single_u(w, 0, Ua);
        single_u(w, 3, Ub);
        kron22(Ua, Ub, Pre);
    } else {
        single_u(w, 3 * (q + 1), Ub);
        kron22(I2m, Ub, Pre);
    }
    if (q == NGATES - 1) {
        single_u(w, L2OFF + 3 * 18, Ua);
        single_u(w, L2OFF + 3 * 19, Ub);
        kron22(Ua, Ub, Post);
    } else {
        single_u(w, L2OFF + 3 * q, Ua);
        kron22(Ua, I2m, Post);
    }
    c32 T2[4][4], Gq[4][4];
    mm4(M, Pre, T2);
    mm4(Post, T2, Gq);
    for (int i = 0; i < 4; i++)
        for (int j = 0; j < 4; j++)
            G[q * 16 + i * 4 + j] = Gq[i][j];
}

// apply4: 4x4 complex gate on 4 amplitudes, index = hi_bit*2 + lo_bit.
__device__ __forceinline__ void apply4(const c32* g, c32& x0, c32& x1, c32& x2, c32& x3) {
    c32 r0 = cmul(g[0],  x0); r0 = cmadd(r0, g[1],  x1); r0 = cmadd(r0, g[2],  x2); r0 = cmadd(r0, g[3],  x3);
    c32 r1 = cmul(g[4],  x0); r1 = cmadd(r1, g[5],  x1); r1 = cmadd(r1, g[6],  x2); r1 = cmadd(r1, g[7],  x3);
    c32 r2 = cmul(g[8],  x0); r2 = cmadd(r2, g[9],  x1); r2 = cmadd(r2, g[10], x2); r2 = cmadd(r2, g[11], x3);
    c32 r3 = cmul(g[12], x0); r3 = cmadd(r3, g[13], x1); r3 = cmadd(r3, g[14], x2); r3 = cmadd(r3, g[15], x3);
    x0 = r0; x1 = r1; x2 = r2; x3 = r3;
}
__device__ __forceinline__ void load_gate(const c32* __restrict__ gp, c32 g[16]) {
#pragma unroll
    for (int k = 0; k < 16; k++) g[k] = gp[k];
}
// Three staircase gates acting on owned-nibble bits (j3,j2), (j2,j1), (j1,j0).
__device__ __forceinline__ void phase3(c32 v[16], const c32* __restrict__ Ga,
                                       const c32* __restrict__ Gb, const c32* __restrict__ Gc) {
    c32 g[16];
    load_gate(Ga, g);
#pragma unroll
    for (int n = 0; n < 4; n++) apply4(g, v[n], v[n + 4], v[n + 8], v[n + 12]);
    load_gate(Gb, g);
#pragma unroll
    for (int h = 0; h < 2; h++)
#pragma unroll
        for (int n = 0; n < 2; n++) apply4(g, v[8 * h + n], v[8 * h + n + 2], v[8 * h + n + 4], v[8 * h + n + 6]);
    load_gate(Gc, g);
#pragma unroll
    for (int bq = 0; bq < 4; bq++) apply4(g, v[4 * bq], v[4 * bq + 1], v[4 * bq + 2], v[4 * bq + 3]);
}

// Pass A: gates 0..7 (psi bits 19..11). State viewed as [512 rows = top-9 bits][2048 cols].
// Block: [512][16-col] c32 tile in LDS (pad 17), reads x (real), writes psi. 512 blocks.
__global__ __launch_bounds__(256) void pass_a(const float* __restrict__ x,
                                              c32* __restrict__ psi,
                                              const c32* __restrict__ Gall) {
    __shared__ c32 s[512][17];   // 69632 B
    int b = blockIdx.x >> 7;
    int c0 = (blockIdx.x & 127) << 4;
    const float* xp = x + ((size_t)b << 20) + c0;
    c32* pp = psi + ((size_t)b << 20) + c0;
#pragma unroll
    for (int p = 0; p < 8; ++p) {
        int idx = threadIdx.x + (p << 8);
        int r = idx >> 2;
        int c4 = (idx & 3) << 2;
        float4 v = *reinterpret_cast<const float4*>(xp + ((size_t)r << 11) + c4);
        s[r][c4 + 0] = make_float2(v.x, 0.f);
        s[r][c4 + 1] = make_float2(v.y, 0.f);
        s[r][c4 + 2] = make_float2(v.z, 0.f);
        s[r][c4 + 3] = make_float2(v.w, 0.f);
    }
    __syncthreads();
#pragma unroll
    for (int q = 0; q < 8; ++q) {
        const int b0 = 7 - q;         // lower bit of local row pair
        c32 g[16];
        load_gate(Gall + q * 16, g);
#pragma unroll
        for (int p = 0; p < 8; ++p) {
            int task = threadIdx.x + (p << 8);
            int c = task & 15;
            int grp = task >> 4;      // 128 groups of 4 rows
            int l0 = ((grp >> b0) << (b0 + 2)) | (grp & ((1 << b0) - 1));
            const int st = 1 << b0;
            apply4(g, s[l0][c], s[l0 + st][c], s[l0 + 2 * st][c], s[l0 + 3 * st][c]);
        }
        __syncthreads();
    }
#pragma unroll
    for (int p = 0; p < 16; ++p) {
        int idx = threadIdx.x + (p << 8);
        int r = idx >> 3;
        int c2 = (idx & 7) << 1;
        float4 v = make_float4(s[r][c2].x, s[r][c2].y, s[r][c2 + 1].x, s[r][c2 + 1].y);
        *reinterpret_cast<float4*>(pp + ((size_t)r << 11) + c2) = v;
    }
}

// Pass B: gates 8..18 (psi bits 11..0). Block owns 4096 contiguous amps.
// 4 register-ownership phases (bits 11..8 / 8..5 / 5..2 / 3..0), 3 LDS roundtrips.
#define PB_PIDX(l) ((l) + ((l) >> 4) + ((l) >> 8))
__global__ __launch_bounds__(256) void pass_b(c32* __restrict__ psi, const c32* __restrict__ Gall) {
    __shared__ c32 s[4368];      // 4096 + pads
    int t = threadIdx.x;
    c32* pp = psi + ((size_t)blockIdx.x << 12);
    c32 v[16];
    // Own-A: l = (j<<8)|t  (bits 11..8 owned) -- coalesced global load
#pragma unroll
    for (int j = 0; j < 16; ++j) v[j] = pp[(j << 8) | t];
    phase3(v, Gall + 8 * 16, Gall + 9 * 16, Gall + 10 * 16);
#pragma unroll
    for (int j = 0; j < 16; ++j) { int l = (j << 8) | t; s[PB_PIDX(l)] = v[j]; }
    __syncthreads();
    // Own-B: l = t_hi<<9 | j<<5 | t_lo (bits 8..5 owned)
    int hiB = (t >> 5) << 9, loB = t & 31;
#pragma unroll
    for (int j = 0; j < 16; ++j) { int l = hiB | (j << 5) | loB; v[j] = s[PB_PIDX(l)]; }
    phase3(v, Gall + 11 * 16, Gall + 12 * 16, Gall + 13 * 16);
#pragma unroll
    for (int j = 0; j < 16; ++j) { int l = hiB | (j << 5) | loB; s[PB_PIDX(l)] = v[j]; }
    __syncthreads();
    // Own-C: l = t_hi<<6 | j<<2 | t_lo (bits 5..2 owned)
    int hiC = (t >> 2) << 6, loC = t & 3;
#pragma unroll
    for (int j = 0; j < 16; ++j) { int l = hiC | (j << 2) | loC; v[j] = s[PB_PIDX(l)]; }
    phase3(v, Gall + 14 * 16, Gall + 15 * 16, Gall + 16 * 16);
#pragma unroll
    for (int j = 0; j < 16; ++j) { int l = hiC | (j << 2) | loC; s[PB_PIDX(l)] = v[j]; }
    __syncthreads();
    // Own-D: l = t<<4 | j (bits 3..0 owned) -- gates 17 (j2,j1), 18 (j1,j0)
#pragma unroll
    for (int j = 0; j < 16; ++j) { int l = (t << 4) | j; v[j] = s[PB_PIDX(l)]; }
    {
        c32 g[16];
        load_gate(Gall + 17 * 16, g);
#pragma unroll
        for (int h = 0; h < 2; h++)
#pragma unroll
            for (int n = 0; n < 2; n++) apply4(g, v[8 * h + n], v[8 * h + n + 2], v[8 * h + n + 4], v[8 * h + n + 6]);
        load_gate(Gall + 18 * 16, g);
#pragma unroll
        for (int bq = 0; bq < 4; bq++) apply4(g, v[4 * bq], v[4 * bq + 1], v[4 * bq + 2], v[4 * bq + 3]);
    }
#pragma unroll
    for (int k = 0; k < 8; ++k)
        *reinterpret_cast<float4*>(pp + (t << 4) + 2 * k) =
            make_float4(v[2 * k].x, v[2 * k].y, v[2 * k + 1].x, v[2 * k + 1].y);
}

// Transpose + bf16 cast: psi[b][t][a] c32 -> Art[b][a][t], Ait[b][a][t] bf16.
__global__ __launch_bounds__(256) void conv_transpose(const c32* __restrict__ psi,
                                                      unsigned short* __restrict__ Art,
                                                      unsigned short* __restrict__ Ait) {
    __shared__ c32 lds[64][65];
    int b  = blockIdx.z;
    int t0 = blockIdx.x * 64;
    int a0 = blockIdx.y * 64;
    const c32* P = psi + ((size_t)b << 20);
#pragma unroll
    for (int p = 0; p < 8; ++p) {
        int idx = threadIdx.x + p * 256;
        int t = idx >> 5;
        int a2 = (idx & 31) * 2;
        float4 v = *reinterpret_cast<const float4*>(P + ((size_t)(t0 + t) << 10) + a0 + a2);
        lds[t][a2]     = make_float2(v.x, v.y);
        lds[t][a2 + 1] = make_float2(v.z, v.w);
    }
    __syncthreads();
#pragma unroll
    for (int p = 0; p < 2; ++p) {
        int idx = threadIdx.x + p * 256;
        int a = idx >> 3;
        int tc = (idx & 7) * 8;
        unsigned short rr[8], ri[8];
#pragma unroll
        for (int i = 0; i < 8; ++i) {
            c32 v = lds[tc + i][a];
            rr[i] = f2bf(v.x);
            ri[i] = f2bf(v.y);
        }
        size_t o = ((size_t)b << 20) + ((size_t)(a0 + a) << 10) + t0 + tc;
        *reinterpret_cast<float4*>(Art + o) = *reinterpret_cast<float4*>(rr);
        *reinterpret_cast<float4*>(Ait + o) = *reinterpret_cast<float4*>(ri);
    }
}

// MFMA Gram: rdm[a,c] = sum_t psi[t,a]*conj(psi[t,c])  (unchanged from round 2)
#define LDP 72
__global__ __launch_bounds__(256) void gram_mfma(const unsigned short* __restrict__ Art,
                                                 const unsigned short* __restrict__ Ait,
                                                 float2* __restrict__ out) {
    __shared__ unsigned short ldsRr[64 * LDP], ldsRi[64 * LDP];
    __shared__ unsigned short ldsCr[64 * LDP], ldsCi[64 * LDP];
    int b = blockIdx.y;
    int rem = blockIdx.x;
    int ia = 0;
    while (rem >= 16 - ia) { rem -= 16 - ia; ++ia; }
    int ic = ia + rem;
    int a0 = ia * 64, c0 = ic * 64;

    int lane = threadIdx.x & 63;
    int w = threadIdx.x >> 6;
    int wr = (w >> 1) * 32, wc = (w & 1) * 32;
    int lrow = lane & 15;
    int lk   = (lane >> 4) * 8;

    f32x4 accS[2][2], accP1[2][2], accP2[2][2];
#pragma unroll
    for (int m = 0; m < 2; m++)
#pragma unroll
        for (int n = 0; n < 2; n++) {
            accS[m][n] = (f32x4)0.f; accP1[m][n] = (f32x4)0.f; accP2[m][n] = (f32x4)0.f;
        }

    size_t gb = (size_t)b << 20;
    for (int k0 = 0; k0 < 1024; k0 += 64) {
        __syncthreads();
#pragma unroll
        for (int s = 0; s < 2; ++s) {
            int cchunk = threadIdx.x + s * 256;
            int row = cchunk >> 3;
            int col = (cchunk & 7) * 8;
            size_t gR = gb + ((size_t)(a0 + row) << 10) + k0 + col;
            size_t gC = gb + ((size_t)(c0 + row) << 10) + k0 + col;
            float4 vRr = *reinterpret_cast<const float4*>(Art + gR);
            float4 vRi = *reinterpret_cast<const float4*>(Ait + gR);
            float4 vCr = *reinterpret_cast<const float4*>(Art + gC);
            float4 vCi = *reinterpret_cast<const float4*>(Ait + gC);
            int la = row * LDP + col;
            *reinterpret_cast<float4*>(ldsRr + la) = vRr;
            *reinterpret_cast<float4*>(ldsRi + la) = vRi;
            *reinterpret_cast<float4*>(ldsCr + la) = vCr;
            *reinterpret_cast<float4*>(ldsCi + la) = vCi;
        }
        __syncthreads();
#pragma unroll
        for (int kk = 0; kk < 2; ++kk) {
            int ko = kk * 32 + lk;
            short8 ar[2], ai[2], br[2], bi[2];
#pragma unroll
            for (int m = 0; m < 2; m++) {
                int r = (wr + m * 16 + lrow) * LDP + ko;
                ar[m] = *reinterpret_cast<const short8*>(ldsRr + r);
                ai[m] = *reinterpret_cast<const short8*>(ldsRi + r);
            }
#pragma unroll
            for (int n = 0; n < 2; n++) {
                int r = (wc + n * 16 + lrow) * LDP + ko;
                br[n] = *reinterpret_cast<const short8*>(ldsCr + r);
                bi[n] = *reinterpret_cast<const short8*>(ldsCi + r);
            }
#pragma unroll
            for (int m = 0; m < 2; m++)
#pragma unroll
                for (int n = 0; n < 2; n++) {
                    accS[m][n]  = __builtin_amdgcn_mfma_f32_16x16x32_bf16(ar[m], br[n], accS[m][n], 0, 0, 0);
                    accS[m][n]  = __builtin_amdgcn_mfma_f32_16x16x32_bf16(ai[m], bi[n], accS[m][n], 0, 0, 0);
                    accP1[m][n] = __builtin_amdgcn_mfma_f32_16x16x32_bf16(ai[m], br[n], accP1[m][n], 0, 0, 0);
                    accP2[m][n] = __builtin_amdgcn_mfma_f32_16x16x32_bf16(ar[m], bi[n], accP2[m][n], 0, 0, 0);
                }
        }
    }
    size_t ob = (size_t)b << 20;
#pragma unroll
    for (int m = 0; m < 2; m++)
#pragma unroll
        for (int n = 0; n < 2; n++)
#pragma unroll
            for (int r = 0; r < 4; r++) {
                int a = a0 + wr + m * 16 + (lane >> 4) * 4 + r;
                int c = c0 + wc + n * 16 + (lane & 15);
                float re = accS[m][n][r];
                float im = accP1[m][n][r] - accP2[m][n][r];
                out[ob + ((size_t)a << 10) + c] = make_float2(re, im);
                if (ia != ic)
                    out[ob + ((size_t)c << 10) + a] = make_float2(re, -im);
            }
}

// fp32 fallback gram, used only if ws_size can't hold Art/Ait.
__global__ __launch_bounds__(256) void gram_f32(const c32* __restrict__ psi, float2* __restrict__ out) {
    __shared__ c32 At[16][65];
    __shared__ c32 Ct[16][65];
    int b = blockIdx.y;
    int rem = blockIdx.x;
    int ia = 0;
    while (rem >= 16 - ia) { rem -= 16 - ia; ++ia; }
    int ic = ia + rem;
    int a0 = ia * 64, c0 = ic * 64;
    int tx = threadIdx.x & 15, ty = threadIdx.x >> 4;
    float accr[4][4] = {}, acci[4][4] = {};
    const c32* P = psi + ((size_t)b << 20);
    for (int tch = 0; tch < 1024; tch += 16) {
        int e = threadIdx.x * 2;
        int r1 = e >> 6, col = e & 63;
        int r2 = r1 + 8;
        float4 va1 = *reinterpret_cast<const float4*>(P + (size_t)(tch + r1) * 1024 + a0 + col);
        float4 va2 = *reinterpret_cast<const float4*>(P + (size_t)(tch + r2) * 1024 + a0 + col);
        float4 vc1 = *reinterpret_cast<const float4*>(P + (size_t)(tch + r1) * 1024 + c0 + col);
        float4 vc2 = *reinterpret_cast<const float4*>(P + (size_t)(tch + r2) * 1024 + c0 + col);
        At[r1][col] = make_float2(va1.x, va1.y);
        At[r1][col + 1] = make_float2(va1.z, va1.w);
        At[r2][col] = make_float2(va2.x, va2.y);
        At[r2][col + 1] = make_float2(va2.z, va2.w);
        Ct[r1][col] = make_float2(vc1.x, vc1.y);
        Ct[r1][col + 1] = make_float2(vc1.z, vc1.w);
        Ct[r2][col] = make_float2(vc2.x, vc2.y);
        Ct[r2][col + 1] = make_float2(vc2.z, vc2.w);
        __syncthreads();
#pragma unroll
        for (int tt = 0; tt < 16; ++tt) {
            c32 av[4], cv[4];
#pragma unroll
            for (int i = 0; i < 4; i++) av[i] = At[tt][ty * 4 + i];
#pragma unroll
            for (int j = 0; j < 4; j++) cv[j] = Ct[tt][tx * 4 + j];
#pragma unroll
            for (int i = 0; i < 4; i++)
#pragma unroll
                for (int j = 0; j < 4; j++) {
                    accr[i][j] = fmaf(av[i].x, cv[j].x, fmaf(av[i].y, cv[j].y, accr[i][j]));
                    acci[i][j] = fmaf(av[i].y, cv[j].x, fmaf(-av[i].x, cv[j].y, acci[i][j]));
                }
        }
        __syncthreads();
    }
    size_t ob = (size_t)b << 20;
#pragma unroll
    for (int i = 0; i < 4; i++) {
        int a = a0 + ty * 4 + i;
#pragma unroll
        for (int j = 0; j < 4; j++) {
            int c = c0 + tx * 4 + j;
            out[ob + ((size_t)a << 10) + c] = make_float2(accr[i][j], acci[i][j]);
        }
    }
    if (ia != ic) {
#pragma unroll
        for (int i = 0; i < 4; i++) {
            int a = a0 + ty * 4 + i;
#pragma unroll
            for (int j = 0; j < 4; j++) {
                int c = c0 + tx * 4 + j;
                out[ob + ((size_t)c << 10) + a] = make_float2(accr[i][j], -acci[i][j]);
            }
        }
    }
}

extern "C" void kernel_launch(void* const* d_in, const int* in_sizes, int n_in,
                              void* d_out, int out_size, void* d_ws, size_t ws_size,
                              hipStream_t stream) {
    const float* x = (const float*)d_in[0];
    const float* weight = (const float*)d_in[1];
    const size_t psiBytes = (size_t)BATCH * DIM * sizeof(c32);       // 32 MB
    c32* psi = (c32*)d_ws;
    c32* G = (c32*)((char*)d_ws + psiBytes);
    unsigned short* Art = (unsigned short*)((char*)d_ws + psiBytes + 65536);
    unsigned short* Ait = Art + (size_t)BATCH * DIM;                 // 8 MB each
    const size_t needed = psiBytes + 65536 + 2 * (size_t)BATCH * DIM * sizeof(unsigned short);

    build_gates<<<1, 64, 0, stream>>>(weight, G);
    pass_a<<<BATCH * 128, 256, 0, stream>>>(x, psi, G);   // gates 0..7
    pass_b<<<BATCH * 256, 256, 0, stream>>>(psi, G);      // gates 8..18

    if (ws_size >= needed) {
        conv_transpose<<<dim3(16, 16, BATCH), 256, 0, stream>>>(psi, Art, Ait);
        gram_mfma<<<dim3(136, BATCH), 256, 0, stream>>>(Art, Ait, (float2*)d_out);
    } else {
        gram_f32<<<dim3(136, BATCH), 256, 0, stream>>>(psi, (float2*)d_out);
    }
}

// Round 4
// 105.897 us; speedup vs baseline: 4.9401x; 1.0866x over previous
//
#include <hip/hip_runtime.h>
#include <hip/hip_bf16.h>

#define N_Q    20
#define DIM    (1 << N_Q)      // 1048576
#define BATCH  4
#define NGATES 19
#define L2OFF  117             // 6n-3 : second xyz layer offset

typedef float2 c32;
typedef __attribute__((ext_vector_type(8))) short short8;
typedef __attribute__((ext_vector_type(4))) float f32x4;

__device__ __forceinline__ c32 cmul(c32 a, c32 b) {
    return make_float2(fmaf(a.x, b.x, -a.y * b.y), fmaf(a.x, b.y, a.y * b.x));
}
__device__ __forceinline__ c32 cmadd(c32 acc, c32 a, c32 b) {
    acc.x = fmaf(a.x, b.x, fmaf(-a.y, b.y, acc.x));
    acc.y = fmaf(a.x, b.y, fmaf(a.y, b.x, acc.y));
    return acc;
}
__device__ __forceinline__ unsigned short f2bf(float f) {
    union { float f; unsigned u; } v; v.f = f;
    unsigned r = v.u + 0x7FFFu + ((v.u >> 16) & 1u);
    return (unsigned short)(r >> 16);
}

__device__ void mm2(const c32 A[2][2], const c32 B[2][2], c32 C[2][2]) {
    for (int i = 0; i < 2; i++)
        for (int j = 0; j < 2; j++) {
            c32 s = make_float2(0.f, 0.f);
            for (int k = 0; k < 2; k++) s = cmadd(s, A[i][k], B[k][j]);
            C[i][j] = s;
        }
}
__device__ void mm4(const c32 A[4][4], const c32 B[4][4], c32 C[4][4]) {
    for (int i = 0; i < 4; i++)
        for (int j = 0; j < 4; j++) {
            c32 s = make_float2(0.f, 0.f);
            for (int k = 0; k < 4; k++) s = cmadd(s, A[i][k], B[k][j]);
            C[i][j] = s;
        }
}
__device__ void single_u(const float* w, int base, c32 U[2][2]) {
    const float WM = 0.63245553203367586640f;  // sqrt(2/5)
    float hx = w[base] * WM * 0.5f, hy = w[base + 1] * WM * 0.5f, hz = w[base + 2] * WM * 0.5f;
    float cx = cosf(hx), sx = sinf(hx);
    float cy = cosf(hy), sy = sinf(hy);
    float cz = cosf(hz), sz = sinf(hz);
    c32 RX[2][2] = {{{cx, 0.f}, {0.f, -sx}}, {{0.f, -sx}, {cx, 0.f}}};
    c32 RY[2][2] = {{{cy, 0.f}, {-sy, 0.f}}, {{sy, 0.f}, {cy, 0.f}}};
    c32 RZ[2][2] = {{{cz, -sz}, {0.f, 0.f}}, {{0.f, 0.f}, {cz, sz}}};
    c32 T[2][2];
    mm2(RY, RX, T);
    mm2(RZ, T, U);
}
__device__ void kron22(const c32 A[2][2], const c32 B[2][2], c32 K[4][4]) {
    for (int i = 0; i < 2; i++)
        for (int j = 0; j < 2; j++)
            for (int k = 0; k < 2; k++)
                for (int l = 0; l < 2; l++)
                    K[i * 2 + j][k * 2 + l] = cmul(A[i][k], B[j][l]);
}

// Build the 19 fused 4x4 staircase gates (round-0 derivation).
__global__ void build_gates(const float* __restrict__ w, c32* __restrict__ G) {
    int q = threadIdx.x;
    if (q >= NGATES) return;
    const float WM = 0.63245553203367586640f;
    float hx = w[60 + 3 * q] * WM * 0.5f;
    float hy = w[61 + 3 * q] * WM * 0.5f;
    float hz = w[62 + 3 * q] * WM * 0.5f;
    float cx = cosf(hx), sx = sinf(hx);
    float cy = cosf(hy), sy = sinf(hy);
    float cz = cosf(hz), sz = sinf(hz);
    c32 RXX[4][4], RYY[4][4], RZZ[4][4];
    for (int i = 0; i < 4; i++)
        for (int j = 0; j < 4; j++) {
            RXX[i][j] = make_float2(0.f, 0.f);
            RYY[i][j] = make_float2(0.f, 0.f);
            RZZ[i][j] = make_float2(0.f, 0.f);
        }
    for (int i = 0; i < 4; i++) {
        RXX[i][i]     = make_float2(cx, 0.f);
        RXX[i][3 - i] = make_float2(0.f, -sx);
        RYY[i][i]     = make_float2(cy, 0.f);
    }
    RYY[0][3] = make_float2(0.f,  sy);
    RYY[1][2] = make_float2(0.f, -sy);
    RYY[2][1] = make_float2(0.f, -sy);
    RYY[3][0] = make_float2(0.f,  sy);
    RZZ[0][0] = make_float2(cz, -sz);
    RZZ[1][1] = make_float2(cz,  sz);
    RZZ[2][2] = make_float2(cz,  sz);
    RZZ[3][3] = make_float2(cz, -sz);
    c32 T[4][4], M[4][4];
    mm4(RYY, RXX, T);
    mm4(RZZ, T, M);

    c32 I2m[2][2] = {{{1.f, 0.f}, {0.f, 0.f}}, {{0.f, 0.f}, {1.f, 0.f}}};
    c32 Ua[2][2], Ub[2][2], Pre[4][4], Post[4][4];
    if (q == 0) {
        single_u(w, 0, Ua);
        single_u(w, 3, Ub);
        kron22(Ua, Ub, Pre);
    } else {
        single_u(w, 3 * (q + 1), Ub);
        kron22(I2m, Ub, Pre);
    }
    if (q == NGATES - 1) {
        single_u(w, L2OFF + 3 * 18, Ua);
        single_u(w, L2OFF + 3 * 19, Ub);
        kron22(Ua, Ub, Post);
    } else {
        single_u(w, L2OFF + 3 * q, Ua);
        kron22(Ua, I2m, Post);
    }
    c32 T2[4][4], Gq[4][4];
    mm4(M, Pre, T2);
    mm4(Post, T2, Gq);
    for (int i = 0; i < 4; i++)
        for (int j = 0; j < 4; j++)
            G[q * 16 + i * 4 + j] = Gq[i][j];
}

__device__ __forceinline__ void apply4(const c32* g, c32& x0, c32& x1, c32& x2, c32& x3) {
    c32 r0 = cmul(g[0],  x0); r0 = cmadd(r0, g[1],  x1); r0 = cmadd(r0, g[2],  x2); r0 = cmadd(r0, g[3],  x3);
    c32 r1 = cmul(g[4],  x0); r1 = cmadd(r1, g[5],  x1); r1 = cmadd(r1, g[6],  x2); r1 = cmadd(r1, g[7],  x3);
    c32 r2 = cmul(g[8],  x0); r2 = cmadd(r2, g[9],  x1); r2 = cmadd(r2, g[10], x2); r2 = cmadd(r2, g[11], x3);
    c32 r3 = cmul(g[12], x0); r3 = cmadd(r3, g[13], x1); r3 = cmadd(r3, g[14], x2); r3 = cmadd(r3, g[15], x3);
    x0 = r0; x1 = r1; x2 = r2; x3 = r3;
}
__device__ __forceinline__ void load_gate(const c32* __restrict__ gp, c32 g[16]) {
#pragma unroll
    for (int k = 0; k < 16; k++) g[k] = gp[k];
}
// gate on bits (LO+1, LO) of a 32-amp owned index (compile-time indices only)
template <int LO>
__device__ __forceinline__ void gate_on32(c32 v[32], const c32 g[16]) {
#pragma unroll
    for (int m = 0; m < 8; ++m) {
        const int j0 = ((m >> LO) << (LO + 2)) | (m & ((1 << LO) - 1));
        const int s = 1 << LO;
        apply4(g, v[j0], v[j0 + s], v[j0 + 2 * s], v[j0 + 3 * s]);
    }
}
// gate on bits (LO+1, LO) of a 16-amp owned sub-array
template <int LO>
__device__ __forceinline__ void gate_on16(c32* v, const c32 g[16]) {
#pragma unroll
    for (int m = 0; m < 4; ++m) {
        const int j0 = ((m >> LO) << (LO + 2)) | (m & ((1 << LO) - 1));
        const int s = 1 << LO;
        apply4(g, v[j0], v[j0 + s], v[j0 + 2 * s], v[j0 + 3 * s]);
    }
}

// XOR swizzle for 8192-c32 LDS exchanges: bijective, 0 memory overhead,
// verified 4-way (= b64 floor) for every store/load pattern below.
#define SIDX(l) ((l) ^ ((((l) >> 5) & 15)))

// Pass A2: gates 0..6 (psi bits 19..12). State = [256 rows = bits 19..12][4096 cols].
// Block: 256 rows x 32 cols = 8192 amps. Reads x (real), writes psi (c32).
// Phase 1: own row bits 7..3 (global 19..15) -> gates 0..3 in registers.
// Phase 2: own row bits 3..0 (global 15..12) -> gates 4..6 (2x16-amp halves).
__global__ __launch_bounds__(256) void pass_a2(const float* __restrict__ x,
                                               c32* __restrict__ psi,
                                               const c32* __restrict__ Gall) {
    __shared__ c32 s[8192];      // 64 KB exactly
    int b = blockIdx.x >> 7;
    int c0 = (blockIdx.x & 127) << 5;
    const float* xp = x + ((size_t)b << 20) + c0;
    c32* pp = psi + ((size_t)b << 20) + c0;
    int t = threadIdx.x;
    int col = t & 31, rlow = t >> 5;          // rlow = row bits 2..0 (global 14..12)
    c32 v[32], g[16];
#pragma unroll
    for (int j = 0; j < 32; ++j) {
        int row = (j << 3) | rlow;
        v[j] = make_float2(xp[(size_t)row * 4096 + col], 0.f);
    }
    load_gate(Gall + 0 * 16, g);  gate_on32<3>(v, g);
    load_gate(Gall + 1 * 16, g);  gate_on32<2>(v, g);
    load_gate(Gall + 2 * 16, g);  gate_on32<1>(v, g);
    load_gate(Gall + 3 * 16, g);  gate_on32<0>(v, g);
#pragma unroll
    for (int j = 0; j < 32; ++j) {
        int l = ((((j << 3) | rlow) << 5)) | col;
        s[SIDX(l)] = v[j];
    }
    __syncthreads();
    int rhi = t >> 5;                          // row bits 6..4
#pragma unroll
    for (int rtop = 0; rtop < 2; ++rtop)
#pragma unroll
        for (int j = 0; j < 16; ++j) {
            int row = (rtop << 7) | (rhi << 4) | j;
            int l = (row << 5) | col;
            v[rtop * 16 + j] = s[SIDX(l)];
        }
    load_gate(Gall + 4 * 16, g);  gate_on16<2>(v, g);  gate_on16<2>(v + 16, g);
    load_gate(Gall + 5 * 16, g);  gate_on16<1>(v, g);  gate_on16<1>(v + 16, g);
    load_gate(Gall + 6 * 16, g);  gate_on16<0>(v, g);  gate_on16<0>(v + 16, g);
#pragma unroll
    for (int rtop = 0; rtop < 2; ++rtop)
#pragma unroll
        for (int j = 0; j < 16; ++j) {
            int row = (rtop << 7) | (rhi << 4) | j;
            pp[(size_t)row * 4096 + col] = v[rtop * 16 + j];
        }
}

// Pass B2: gates 7..18 (psi bits 12..0). Block = one 8192-amp contiguous chunk.
// 3 register phases (own bits 12..8 / 8..4 / 4..0), 2 LDS exchanges.
// Output written directly as planar bf16 [t][a] (Brt, Bit).
__global__ __launch_bounds__(256) void pass_b2(const c32* __restrict__ psi,
                                               unsigned short* __restrict__ Brt,
                                               unsigned short* __restrict__ Bit,
                                               const c32* __restrict__ Gall) {
    __shared__ c32 s[8192];
    int b = blockIdx.x >> 7;
    int chunk = blockIdx.x & 127;
    const c32* pp = psi + ((size_t)b << 20) + ((size_t)chunk << 13);
    int t = threadIdx.x;
    c32 v[32], g[16];
    // Phase 1: l = (j<<8)|t, own bits 12..8 -> gates 7..10
#pragma unroll
    for (int j = 0; j < 32; ++j) v[j] = pp[(j << 8) | t];
    load_gate(Gall + 7 * 16, g);   gate_on32<3>(v, g);
    load_gate(Gall + 8 * 16, g);   gate_on32<2>(v, g);
    load_gate(Gall + 9 * 16, g);   gate_on32<1>(v, g);
    load_gate(Gall + 10 * 16, g);  gate_on32<0>(v, g);
#pragma unroll
    for (int j = 0; j < 32; ++j) { int l = (j << 8) | t; s[SIDX(l)] = v[j]; }
    __syncthreads();
    // Phase 2: l = (t>>4)<<9 | j<<4 | (t&15), own bits 8..4 -> gates 11..14
    int hi2 = (t >> 4) << 9, lo2 = t & 15;
#pragma unroll
    for (int j = 0; j < 32; ++j) { int l = hi2 | (j << 4) | lo2; v[j] = s[SIDX(l)]; }
    load_gate(Gall + 11 * 16, g);  gate_on32<3>(v, g);
    load_gate(Gall + 12 * 16, g);  gate_on32<2>(v, g);
    load_gate(Gall + 13 * 16, g);  gate_on32<1>(v, g);
    load_gate(Gall + 14 * 16, g);  gate_on32<0>(v, g);
    __syncthreads();
#pragma unroll
    for (int j = 0; j < 32; ++j) { int l = hi2 | (j << 4) | lo2; s[SIDX(l)] = v[j]; }
    __syncthreads();
    // Phase 3: l = (t<<5)|j, own bits 4..0 -> gates 15..18
#pragma unroll
    for (int j = 0; j < 32; ++j) { int l = (t << 5) | j; v[j] = s[SIDX(l)]; }
    load_gate(Gall + 15 * 16, g);  gate_on32<3>(v, g);
    load_gate(Gall + 16 * 16, g);  gate_on32<2>(v, g);
    load_gate(Gall + 17 * 16, g);  gate_on32<1>(v, g);
    load_gate(Gall + 18 * 16, g);  gate_on32<0>(v, g);
    // Output: 32 consecutive amps starting at f = chunk<<13 | t<<5 (coalesced)
    size_t off = ((size_t)b << 20) + ((size_t)chunk << 13) + ((size_t)t << 5);
#pragma unroll
    for (int p = 0; p < 4; ++p) {
        unsigned short rr[8], ri[8];
#pragma unroll
        for (int i = 0; i < 8; ++i) {
            rr[i] = f2bf(v[8 * p + i].x);
            ri[i] = f2bf(v[8 * p + i].y);
        }
        *reinterpret_cast<float4*>(Brt + off + 8 * p) = *reinterpret_cast<float4*>(rr);
        *reinterpret_cast<float4*>(Bit + off + 8 * p) = *reinterpret_cast<float4*>(ri);
    }
}

// bf16 transpose: B[t][a] -> A[a][t] for both Re and Im planes, merged as u32 in LDS.
__global__ __launch_bounds__(256) void bt_t(const unsigned short* __restrict__ Brt,
                                            const unsigned short* __restrict__ Bit,
                                            unsigned short* __restrict__ Art,
                                            unsigned short* __restrict__ Ait) {
    __shared__ unsigned lds32[64 * 66];
    int b  = blockIdx.z;
    int t0 = blockIdx.x * 64;
    int a0 = blockIdx.y * 64;
    size_t gb = (size_t)b << 20;
#pragma unroll
    for (int h = 0; h < 2; ++h) {
        int p = threadIdx.x + h * 256;          // 512 tasks
        int r = p >> 3, cq = p & 7;
        size_t src = gb + (size_t)(t0 + r) * 1024 + a0 + cq * 8;
        float4 fr = *reinterpret_cast<const float4*>(Brt + src);
        float4 fi = *reinterpret_cast<const float4*>(Bit + src);
        const unsigned short* ur = reinterpret_cast<const unsigned short*>(&fr);
        const unsigned short* ui = reinterpret_cast<const unsigned short*>(&fi);
#pragma unroll
        for (int i = 0; i < 8; ++i)
            lds32[r * 66 + cq * 8 + i] = (unsigned)ur[i] | ((unsigned)ui[i] << 16);
    }
    __syncthreads();
#pragma unroll
    for (int h = 0; h < 2; ++h) {
        int q = threadIdx.x + h * 256;
        int a = q >> 3, tq = q & 7;
        unsigned short rr[8], ri[8];
#pragma unroll
        for (int i = 0; i < 8; ++i) {
            unsigned w = lds32[(tq * 8 + i) * 66 + a];
            rr[i] = (unsigned short)(w & 0xFFFF);
            ri[i] = (unsigned short)(w >> 16);
        }
        size_t dst = gb + (size_t)(a0 + a) * 1024 + t0 + tq * 8;
        *reinterpret_cast<float4*>(Art + dst) = *reinterpret_cast<float4*>(rr);
        *reinterpret_cast<float4*>(Ait + dst) = *reinterpret_cast<float4*>(ri);
    }
}

// MFMA Gram: rdm[a,c] = sum_t psi[t,a]*conj(psi[t,c])  (unchanged from round 2)
#define LDP 72
__global__ __launch_bounds__(256) void gram_mfma(const unsigned short* __restrict__ Art,
                                                 const unsigned short* __restrict__ Ait,
                                                 float2* __restrict__ out) {
    __shared__ unsigned short ldsRr[64 * LDP], ldsRi[64 * LDP];
    __shared__ unsigned short ldsCr[64 * LDP], ldsCi[64 * LDP];
    int b = blockIdx.y;
    int rem = blockIdx.x;
    int ia = 0;
    while (rem >= 16 - ia) { rem -= 16 - ia; ++ia; }
    int ic = ia + rem;
    int a0 = ia * 64, c0 = ic * 64;

    int lane = threadIdx.x & 63;
    int w = threadIdx.x >> 6;
    int wr = (w >> 1) * 32, wc = (w & 1) * 32;
    int lrow = lane & 15;
    int lk   = (lane >> 4) * 8;

    f32x4 accS[2][2], accP1[2][2], accP2[2][2];
#pragma unroll
    for (int m = 0; m < 2; m++)
#pragma unroll
        for (int n = 0; n < 2; n++) {
            accS[m][n] = (f32x4)0.f; accP1[m][n] = (f32x4)0.f; accP2[m][n] = (f32x4)0.f;
        }

    size_t gb = (size_t)b << 20;
    for (int k0 = 0; k0 < 1024; k0 += 64) {
        __syncthreads();
#pragma unroll
        for (int s = 0; s < 2; ++s) {
            int cchunk = threadIdx.x + s * 256;
            int row = cchunk >> 3;
            int col = (cchunk & 7) * 8;
            size_t gR = gb + ((size_t)(a0 + row) << 10) + k0 + col;
            size_t gC = gb + ((size_t)(c0 + row) << 10) + k0 + col;
            float4 vRr = *reinterpret_cast<const float4*>(Art + gR);
            float4 vRi = *reinterpret_cast<const float4*>(Ait + gR);
            float4 vCr = *reinterpret_cast<const float4*>(Art + gC);
            float4 vCi = *reinterpret_cast<const float4*>(Ait + gC);
            int la = row * LDP + col;
            *reinterpret_cast<float4*>(ldsRr + la) = vRr;
            *reinterpret_cast<float4*>(ldsRi + la) = vRi;
            *reinterpret_cast<float4*>(ldsCr + la) = vCr;
            *reinterpret_cast<float4*>(ldsCi + la) = vCi;
        }
        __syncthreads();
#pragma unroll
        for (int kk = 0; kk < 2; ++kk) {
            int ko = kk * 32 + lk;
            short8 ar[2], ai[2], br[2], bi[2];
#pragma unroll
            for (int m = 0; m < 2; m++) {
                int r = (wr + m * 16 + lrow) * LDP + ko;
                ar[m] = *reinterpret_cast<const short8*>(ldsRr + r);
                ai[m] = *reinterpret_cast<const short8*>(ldsRi + r);
            }
#pragma unroll
            for (int n = 0; n < 2; n++) {
                int r = (wc + n * 16 + lrow) * LDP + ko;
                br[n] = *reinterpret_cast<const short8*>(ldsCr + r);
                bi[n] = *reinterpret_cast<const short8*>(ldsCi + r);
            }
#pragma unroll
            for (int m = 0; m < 2; m++)
#pragma unroll
                for (int n = 0; n < 2; n++) {
                    accS[m][n]  = __builtin_amdgcn_mfma_f32_16x16x32_bf16(ar[m], br[n], accS[m][n], 0, 0, 0);
                    accS[m][n]  = __builtin_amdgcn_mfma_f32_16x16x32_bf16(ai[m], bi[n], accS[m][n], 0, 0, 0);
                    accP1[m][n] = __builtin_amdgcn_mfma_f32_16x16x32_bf16(ai[m], br[n], accP1[m][n], 0, 0, 0);
                    accP2[m][n] = __builtin_amdgcn_mfma_f32_16x16x32_bf16(ar[m], bi[n], accP2[m][n], 0, 0, 0);
                }
        }
    }
    size_t ob = (size_t)b << 20;
#pragma unroll
    for (int m = 0; m < 2; m++)
#pragma unroll
        for (int n = 0; n < 2; n++)
#pragma unroll
            for (int r = 0; r < 4; r++) {
                int a = a0 + wr + m * 16 + (lane >> 4) * 4 + r;
                int c = c0 + wc + n * 16 + (lane & 15);
                float re = accS[m][n][r];
                float im = accP1[m][n][r] - accP2[m][n][r];
                out[ob + ((size_t)a << 10) + c] = make_float2(re, im);
                if (ia != ic)
                    out[ob + ((size_t)c << 10) + a] = make_float2(re, -im);
            }
}

extern "C" void kernel_launch(void* const* d_in, const int* in_sizes, int n_in,
                              void* d_out, int out_size, void* d_ws, size_t ws_size,
                              hipStream_t stream) {
    const float* x = (const float*)d_in[0];
    const float* weight = (const float*)d_in[1];
    const size_t psiBytes = (size_t)BATCH * DIM * sizeof(c32);       // 32 MB
    const size_t planeBytes = (size_t)BATCH * DIM * sizeof(unsigned short);  // 8 MB
    c32* psi = (c32*)d_ws;
    c32* G = (c32*)((char*)d_ws + psiBytes);
    unsigned short* Brt = (unsigned short*)((char*)d_ws + psiBytes + 65536);
    unsigned short* Bit = Brt + (size_t)BATCH * DIM;
    unsigned short* Art = Bit + (size_t)BATCH * DIM;
    unsigned short* Ait = Art + (size_t)BATCH * DIM;

    build_gates<<<1, 64, 0, stream>>>(weight, G);
    pass_a2<<<BATCH * 128, 256, 0, stream>>>(x, psi, G);            // gates 0..6
    pass_b2<<<BATCH * 128, 256, 0, stream>>>(psi, Brt, Bit, G);     // gates 7..18 -> bf16 [t][a]
    bt_t<<<dim3(16, 16, BATCH), 256, 0, stream>>>(Brt, Bit, Art, Ait);
    gram_mfma<<<dim3(136, BATCH), 256, 0, stream>>>(Art, Ait, (float2*)d_out);
}